// Round 15
// baseline (174.909 us; speedup 1.0000x reference)
//
#include <hip/hip_runtime.h>
#include <hip/hip_bf16.h>

#define S_LEN 2048
#define D_MODEL 2048
#define N_HEADS 32
#define N_KV 8
#define HEAD_DIM 64
#define KV_DIM (N_KV * HEAD_DIM)    // 512
#define QKV_N (D_MODEL + 2 * KV_DIM) // 3072

typedef __bf16 bf16_t;
typedef __attribute__((ext_vector_type(8))) __bf16 bf16x8;
typedef __attribute__((ext_vector_type(4))) float f32x4;
typedef __attribute__((ext_vector_type(16))) float f32x16;
typedef __attribute__((ext_vector_type(4))) unsigned int uint4v;
typedef __attribute__((ext_vector_type(2))) unsigned int uint2v;

// ---------------------------------------------------------------------------
// async global->LDS 16B copy. LDS dest must be wave-uniform base + lane*16.
// ---------------------------------------------------------------------------
__device__ __forceinline__ void gload_lds16(const void* g, void* l) {
    __builtin_amdgcn_global_load_lds(
        (const __attribute__((address_space(1))) unsigned char*)g,
        (__attribute__((address_space(3))) unsigned char*)l,
        16, 0, 0);
}

// ---------------------------------------------------------------------------
// Transpose + convert: src [R][C] f32 -> dst [C][R] bf16
// ---------------------------------------------------------------------------
__global__ __launch_bounds__(256) void transpose_convert(const float* __restrict__ src,
                                                         __hip_bfloat16* __restrict__ dst,
                                                         int R, int C) {
    __shared__ float tile[32][33];
    const int bx = blockIdx.x * 32;
    const int by = blockIdx.y * 32;
    const int tx = threadIdx.x;  // 0..31
    const int ty = threadIdx.y;  // 0..7
#pragma unroll
    for (int i = 0; i < 32; i += 8)
        tile[ty + i][tx] = src[(size_t)(by + ty + i) * C + bx + tx];
    __syncthreads();
#pragma unroll
    for (int i = 0; i < 32; i += 8)
        dst[(size_t)(bx + ty + i) * R + by + tx] = __float2bfloat16(tile[tx][ty + i]);
}

// ---------------------------------------------------------------------------
// f32 -> bf16 convert (8 elems/thread)
// ---------------------------------------------------------------------------
__global__ __launch_bounds__(256) void convert_bf16(const float* __restrict__ src,
                                                    __hip_bfloat16* __restrict__ dst) {
    const int i = (blockIdx.x * 256 + threadIdx.x) * 8;
    const float4 a = *reinterpret_cast<const float4*>(src + i);
    const float4 b = *reinterpret_cast<const float4*>(src + i + 4);
    bf16x8 r;
    r[0] = (__bf16)a.x; r[1] = (__bf16)a.y; r[2] = (__bf16)a.z; r[3] = (__bf16)a.w;
    r[4] = (__bf16)b.x; r[5] = (__bf16)b.y; r[6] = (__bf16)b.z; r[7] = (__bf16)b.w;
    *reinterpret_cast<bf16x8*>(dst + i) = r;
}

// ---------------------------------------------------------------------------
// Fused RoPE for Q (32 heads, scaled) and K (8 heads), in-place on QKV.
// ---------------------------------------------------------------------------
__global__ __launch_bounds__(256) void rope_qk(__hip_bfloat16* __restrict__ t,
                                               const float* __restrict__ cos_t,
                                               const float* __restrict__ sin_t) {
    const int idx = blockIdx.x * blockDim.x + threadIdx.x;  // S * 40 * 32
    const int i = idx & 31;
    const int hh = (idx >> 5) % (N_HEADS + N_KV);
    const int s = idx / (32 * (N_HEADS + N_KV));
    const float c = cos_t[s * 32 + i];
    const float sn = sin_t[s * 32 + i];
    int col; float scale;
    if (hh < N_HEADS) { col = hh * HEAD_DIM + 2 * i; scale = 0.125f * 1.44269504f; }
    else { col = D_MODEL + (hh - N_HEADS) * HEAD_DIM + 2 * i; scale = 1.0f; }
    __hip_bfloat16* p = &t[(size_t)s * QKV_N + col];
    const float re = __bfloat162float(p[0]);
    const float im = __bfloat162float(p[1]);
    p[0] = __float2bfloat16((re * c - im * sn) * scale);
    p[1] = __float2bfloat16((re * sn + im * c) * scale);
}

// ---------------------------------------------------------------------------
// V transpose: QKV[s][2560 + hkv*64 + d] -> Vt[(hkv*64+d)][s]
// ---------------------------------------------------------------------------
__global__ __launch_bounds__(256) void transpose_v(const __hip_bfloat16* __restrict__ QKV,
                                                   __hip_bfloat16* __restrict__ Vt) {
    __shared__ __align__(16) __bf16 tile[64][72];
    const int s0 = blockIdx.x * 64;
    const int hkv = blockIdx.y;
    const int tid = threadIdx.x;
    {
        const int r = tid >> 2;
        const int c0 = (tid & 3) * 16;
        const __hip_bfloat16* src = QKV + (size_t)(s0 + r) * QKV_N + D_MODEL + KV_DIM + hkv * HEAD_DIM + c0;
        *reinterpret_cast<bf16x8*>(&tile[r][c0]) = *reinterpret_cast<const bf16x8*>(src);
        *reinterpret_cast<bf16x8*>(&tile[r][c0 + 8]) = *reinterpret_cast<const bf16x8*>(src + 8);
    }
    __syncthreads();
    {
        const int d = tid >> 2;
        const int sc = (tid & 3) * 16;
        bf16x8 o0, o1;
#pragma unroll
        for (int j = 0; j < 8; ++j) { o0[j] = tile[sc + j][d]; o1[j] = tile[sc + 8 + j][d]; }
        __hip_bfloat16* dst = Vt + (size_t)(hkv * HEAD_DIM + d) * S_LEN + s0 + sc;
        *reinterpret_cast<bf16x8*>(dst) = o0;
        *reinterpret_cast<bf16x8*>(dst + 8) = o1;
    }
}

// ---------------------------------------------------------------------------
// GEMM v8: 128x128 tile, BK=32, 4 waves, T4 counted-vmcnt depth-2 pipeline
// with 4-BUFFER ring + unroll 4 (kt&3 compile-time within each unrolled
// group -> static LDS indexing, R9's failure fixed; ~400-instr body, R12's
// I-cache bloat fixed). Iter kt: issue stage((kt+2)&3), compute buf kt&3,
// vmcnt(4) drains ONLY stage(kt+1) -> newest stage stays in flight across
// the barrier, its latency spans 2 compute windows. 64 KB LDS (2 blk/CU).
// T1 1D-grid XCD swizzle kept (neutral, harmless). (row&3) chunk swizzle.
// ---------------------------------------------------------------------------
__device__ inline void storeC(__hip_bfloat16* p, float v) { *p = __float2bfloat16(v); }
__device__ inline void storeC(float* p, float v) { *p = v; }

template <typename OutT>
__global__ __launch_bounds__(256) void gemm_bt(const __hip_bfloat16* __restrict__ A,
                                               const __hip_bfloat16* __restrict__ Bt,
                                               OutT* __restrict__ C,
                                               int M, int N, int K) {
    __shared__ __align__(16) __bf16 As[4][128 * 32];   // 8 KB x4
    __shared__ __align__(16) __bf16 Bs[4][128 * 32];   // 8 KB x4
    const int tid = threadIdx.x;
    const int w = tid >> 6, l = tid & 63;
    const int wr = w >> 1, wc = w & 1;
    const int l4 = l >> 4, l15 = l & 15;

    // T1: XCD chunking, 1D grid, column-major tiles. M=2048 -> 16 bm tiles.
    const int nwg = gridDim.x;
    const int cpx = nwg >> 3;
    const int bid = (int)blockIdx.x;
    const int swz = (bid & 7) * cpx + (bid >> 3);
    const int bm = (swz & 15) * 128;
    const int bn = (swz >> 4) * 128;

    f32x4 acc[4][4];
#pragma unroll
    for (int i = 0; i < 4; ++i)
#pragma unroll
        for (int j = 0; j < 4; ++j) acc[i][j] = (f32x4){0.f, 0.f, 0.f, 0.f};

    const int r0 = tid >> 2;     // staging row within 64-row half
    const int cc0 = tid & 3;     // 16B-chunk index within 32-col row

    // 4 global_load_lds per thread per stage (2 A + 2 B)
    auto stage = [&](int buf, int k0) {
#pragma unroll
        for (int p = 0; p < 2; ++p) {
            const int row = p * 64 + r0;
            const int cs = cc0 ^ (row & 3);   // pre-swizzled source chunk
            gload_lds16(&A[(size_t)(bm + row) * K + k0 + cs * 8], &As[buf][(p * 256 + tid) * 8]);
            gload_lds16(&Bt[(size_t)(bn + row) * K + k0 + cs * 8], &Bs[buf][(p * 256 + tid) * 8]);
        }
    };

    const int nk = K >> 5;       // 64 steps for K=2048
    stage(0, 0);
    stage(1, 32);
    asm volatile("s_waitcnt vmcnt(4)" ::: "memory");   // buf0 ready; buf1 in flight
    __builtin_amdgcn_s_barrier();

#pragma unroll 4
    for (int kt = 0; kt < nk; ++kt) {
        if (kt + 2 < nk) stage((kt + 2) & 3, (kt + 2) * 32);   // prefetch depth 2
        const int cur = kt & 3;                                // static in unrolled group
        bf16x8 a[4], b[4];
#pragma unroll
        for (int mi = 0; mi < 4; ++mi) {
            const int rr = wr * 64 + mi * 16 + l15;
            a[mi] = *reinterpret_cast<const bf16x8*>(&As[cur][rr * 32 + ((l4 ^ (rr & 3))) * 8]);
        }
#pragma unroll
        for (int ni = 0; ni < 4; ++ni) {
            const int rr = wc * 64 + ni * 16 + l15;
            b[ni] = *reinterpret_cast<const bf16x8*>(&Bs[cur][rr * 32 + ((l4 ^ (rr & 3))) * 8]);
        }
#pragma unroll
        for (int mi = 0; mi < 4; ++mi)
#pragma unroll
            for (int ni = 0; ni < 4; ++ni)
                acc[mi][ni] = __builtin_amdgcn_mfma_f32_16x16x32_bf16(a[mi], b[ni], acc[mi][ni], 0, 0, 0);
        if (kt + 1 < nk) {
            if (kt + 2 < nk) asm volatile("s_waitcnt vmcnt(4)" ::: "memory");  // counted: newest stage stays in flight
            else             asm volatile("s_waitcnt vmcnt(0)" ::: "memory");  // tail drain
            __builtin_amdgcn_s_barrier();
        }
    }
#pragma unroll
    for (int mi = 0; mi < 4; ++mi)
#pragma unroll
        for (int ni = 0; ni < 4; ++ni)
#pragma unroll
            for (int r = 0; r < 4; ++r) {
                const int row = bm + wr * 64 + mi * 16 + l4 * 4 + r;
                const int col = bn + wc * 64 + ni * 16 + l15;
                storeC(&C[(size_t)row * N + col], acc[mi][ni][r]);
            }
}

// ---------------------------------------------------------------------------
// permlane32_swap: swaps x[hi lanes] with y[lo lanes].
// VALU-pipe (1.20x vs ds_bpermute, m255). Fallback emulation via shfl.
// ---------------------------------------------------------------------------
#if __has_builtin(__builtin_amdgcn_permlane32_swap)
__device__ __forceinline__ void plswap(unsigned& x, unsigned& y, int) {
    uint2v r = __builtin_amdgcn_permlane32_swap(x, y, false, false);
    x = r[0]; y = r[1];
}
#else
__device__ __forceinline__ void plswap(unsigned& x, unsigned& y, int hi) {
    const unsigned px = __shfl_xor(x, 32, 64);
    const unsigned py = __shfl_xor(y, 32, 64);
    const unsigned nx = hi ? py : x;
    const unsigned ny = hi ? y : px;
    x = nx; y = ny;
}
#endif

__device__ __forceinline__ unsigned cvtpk_bf16(float lo, float hi) {
    unsigned w;
    asm("v_cvt_pk_bf16_f32 %0, %1, %2" : "=v"(w) : "v"(lo), "v"(hi));
    return w;
}
__device__ __forceinline__ float swap_max(float v, int hi) {
    unsigned x = __builtin_bit_cast(unsigned, v), y = x;
    plswap(x, y, hi);
    return fmaxf(__builtin_bit_cast(float, x), __builtin_bit_cast(float, y));
}
__device__ __forceinline__ float swap_add(float v, int hi) {
    unsigned x = __builtin_bit_cast(unsigned, v), y = x;
    plswap(x, y, hi);
    return __builtin_bit_cast(float, x) + __builtin_bit_cast(float, y);
}
// Build PV B-fragment for one 16-kv k-step from 8 own p-values s[R0..R0+7].
template <int R0>
__device__ __forceinline__ bf16x8 build_pfrag(const f32x16& s, int hi) {
    unsigned A0 = cvtpk_bf16(s[R0 + 0], s[R0 + 1]);
    unsigned A1 = cvtpk_bf16(s[R0 + 2], s[R0 + 3]);
    unsigned B0 = cvtpk_bf16(s[R0 + 4], s[R0 + 5]);
    unsigned B1 = cvtpk_bf16(s[R0 + 6], s[R0 + 7]);
    plswap(A0, B0, hi);
    plswap(A1, B1, hi);
    uint4v u; u[0] = A0; u[1] = A1; u[2] = B0; u[3] = B1;
    return __builtin_bit_cast(bf16x8, u);
}

// ---------------------------------------------------------------------------
// Flash attention v11 (unchanged): deep split-KV, slices of 4 tiles
// (256 kv) -> 36 slices/head = 1152 blocks. ns(qc)=qc+1.
// ---------------------------------------------------------------------------
__global__ __launch_bounds__(512) void attn_kernel(const __hip_bfloat16* __restrict__ QKV,
                                                   const __hip_bfloat16* __restrict__ Vt,
                                                   __hip_bfloat16* __restrict__ O,
                                                   __hip_bfloat16* __restrict__ Opart,
                                                   float* __restrict__ ms,
                                                   int split) {
    const int h = blockIdx.y;
    const int hkv = h >> 2;
    int qc = 0, sl = 0, gbase = 0, ns = 1;
    if (!split) {
        qc = 7 - (int)blockIdx.x;
    } else {
        const int x = (int)blockIdx.x;      // 0..35
        int cum = 0;
#pragma unroll
        for (int q = 0; q < 8; ++q) {
            const int n = q + 1;
            if (x >= cum && x < cum + n) { qc = q; sl = x - cum; gbase = cum; }
            cum += n;
        }
        ns = qc + 1;
    }
    const int ntf = 4 * (qc + 1);
    const int t0 = split ? sl * 4 : 0;
    const int t1 = split ? min(t0 + 4, ntf) : ntf;

    const int tid = threadIdx.x;
    const int w = tid >> 6, l = tid & 63;
    const int lq = l & 31, hi = l >> 5;
    const int q0w = qc * 256 + w * 32;
    const int qlane = q0w + lq;

    __shared__ __align__(16) __bf16 Ks[2][64 * 64];  // [kv][d] swizzled
    __shared__ __align__(16) __bf16 Vs[2][64 * 64];  // [d][kv] swizzled

    const __hip_bfloat16* Kg = QKV + D_MODEL + hkv * HEAD_DIM;       // [s][QKV_N]
    const __hip_bfloat16* Vg = Vt + (size_t)hkv * HEAD_DIM * S_LEN;  // [d][S]

    auto stage = [&](int buf, int kv0) {
        const int chunk = tid;                    // 0..511
        const int r = chunk >> 3;                 // row 0..63
        const int cs = (chunk & 7) ^ (r & 7);     // pre-swizzled source chunk
        gload_lds16(&Kg[(size_t)(kv0 + r) * QKV_N + cs * 8], &Ks[buf][chunk * 8]);
        gload_lds16(&Vg[(size_t)r * S_LEN + kv0 + cs * 8], &Vs[buf][chunk * 8]);
    };

    // Q as B-operand: lane holds Q[qlane][16f + 8*hi + e]
    bf16x8 qf[4];
#pragma unroll
    for (int f = 0; f < 4; ++f)
        qf[f] = *reinterpret_cast<const bf16x8*>(
            &QKV[(size_t)qlane * QKV_N + h * HEAD_DIM + 16 * f + 8 * hi]);

    f32x16 o0, o1;
#pragma unroll
    for (int r = 0; r < 16; ++r) { o0[r] = 0.f; o1[r] = 0.f; }
    float m_run = -__builtin_inff(), s_run = 0.f;

    stage(0, t0 * 64);

#pragma unroll 1
    for (int t = t0; t < t1; ++t) {
        __syncthreads();                       // tile t staged (vmcnt drained)
        if (t + 1 < t1) stage((t + 1 - t0) & 1, (t + 1) * 64);
        const int kv0 = t * 64;
        if (kv0 <= q0w + 31) {                 // wave-uniform: skip fully-masked
            const __bf16* Kb = Ks[(t - t0) & 1];
            const __bf16* Vb = Vs[(t - t0) & 1];

            // S^T = K · Q^T  (two 32-kv sub-tiles)
            f32x16 s0, s1;
#pragma unroll
            for (int r = 0; r < 16; ++r) { s0[r] = 0.f; s1[r] = 0.f; }
            __builtin_amdgcn_s_setprio(1);
#pragma unroll
            for (int f = 0; f < 4; ++f) {
                const int rr0 = lq;
                const int rr1 = 32 + lq;
                const bf16x8 ka0 = *reinterpret_cast<const bf16x8*>(
                    &Kb[rr0 * 64 + (((2 * f + hi) ^ (rr0 & 7))) * 8]);
                const bf16x8 ka1 = *reinterpret_cast<const bf16x8*>(
                    &Kb[rr1 * 64 + (((2 * f + hi) ^ (rr1 & 7))) * 8]);
                s0 = __builtin_amdgcn_mfma_f32_32x32x16_bf16(ka0, qf[f], s0, 0, 0, 0);
                s1 = __builtin_amdgcn_mfma_f32_32x32x16_bf16(ka1, qf[f], s1, 0, 0, 0);
            }
            __builtin_amdgcn_s_setprio(0);
            // causal mask (only tiles crossing the diagonal)
            if (kv0 + 63 > q0w) {
#pragma unroll
                for (int r = 0; r < 16; ++r) {
                    const int kvb = (r & 3) + 8 * (r >> 2) + 4 * hi;
                    if (kv0 + kvb > qlane) s0[r] = -__builtin_inff();
                    if (kv0 + 32 + kvb > qlane) s1[r] = -__builtin_inff();
                }
            }
            // row max: tree over own 32 regs, then partner exchange
            float ta = fmaxf(s0[0], s1[0]), tb = fmaxf(s0[1], s1[1]);
            float tc = fmaxf(s0[2], s1[2]), td = fmaxf(s0[3], s1[3]);
#pragma unroll
            for (int r = 4; r < 16; r += 4) {
                ta = fmaxf(ta, fmaxf(s0[r], s1[r]));
                tb = fmaxf(tb, fmaxf(s0[r + 1], s1[r + 1]));
                tc = fmaxf(tc, fmaxf(s0[r + 2], s1[r + 2]));
                td = fmaxf(td, fmaxf(s0[r + 3], s1[r + 3]));
            }
            const float m_row = swap_max(fmaxf(fmaxf(ta, tb), fmaxf(tc, td)), hi);

            // defer-max: skip rescale when max grew by <= 8 (exp2 domain)
            if (!__all(m_row <= m_run + 8.0f)) {
                const float mnew = fmaxf(m_run, m_row);
                const float corr = exp2f(m_run - mnew);
                m_run = mnew;
                s_run *= corr;
#pragma unroll
                for (int r = 0; r < 16; ++r) { o0[r] *= corr; o1[r] *= corr; }
            }
            // P = exp2(S - m_run)
#pragma unroll
            for (int r = 0; r < 16; ++r) {
                s0[r] = exp2f(s0[r] - m_run);
                s1[r] = exp2f(s1[r] - m_run);
            }
            // row sum
            float ua = s0[0] + s1[0], ub = s0[1] + s1[1];
            float uc = s0[2] + s1[2], ud = s0[3] + s1[3];
#pragma unroll
            for (int r = 4; r < 16; r += 4) {
                ua += s0[r] + s1[r];
                ub += s0[r + 1] + s1[r + 1];
                uc += s0[r + 2] + s1[r + 2];
                ud += s0[r + 3] + s1[r + 3];
            }
            s_run += swap_add((ua + ub) + (uc + ud), hi);

            // P fragments (k-steps of 16 kv)
            bf16x8 pa[4];
            pa[0] = build_pfrag<0>(s0, hi);
            pa[1] = build_pfrag<8>(s0, hi);
            pa[2] = build_pfrag<0>(s1, hi);
            pa[3] = build_pfrag<8>(s1, hi);

            // O^T += V^T · P^T
            __builtin_amdgcn_s_setprio(1);
#pragma unroll
            for (int ks = 0; ks < 4; ++ks) {
                const int rv0 = lq;
                const int rv1 = 32 + lq;
                const bf16x8 va0 = *reinterpret_cast<const bf16x8*>(
                    &Vb[rv0 * 64 + (((2 * ks + hi) ^ (rv0 & 7))) * 8]);
                const bf16x8 va1 = *reinterpret_cast<const bf16x8*>(
                    &Vb[rv1 * 64 + (((2 * ks + hi) ^ (rv1 & 7))) * 8]);
                o0 = __builtin_amdgcn_mfma_f32_32x32x16_bf16(va0, pa[ks], o0, 0, 0, 0);
                o1 = __builtin_amdgcn_mfma_f32_32x32x16_bf16(va1, pa[ks], o1, 0, 0, 0);
            }
            __builtin_amdgcn_s_setprio(0);
        }
    }

    if (ns == 1) {
        // direct normalized write: O^T[dv][q] -> O[q][h*64+dv]
        const float inv = 1.0f / s_run;
        __hip_bfloat16* orow = O + (size_t)qlane * D_MODEL + h * HEAD_DIM;
#pragma unroll
        for (int rr = 0; rr < 4; ++rr) {
            {
                uint2v u;
                u[0] = cvtpk_bf16(o0[4 * rr] * inv, o0[4 * rr + 1] * inv);
                u[1] = cvtpk_bf16(o0[4 * rr + 2] * inv, o0[4 * rr + 3] * inv);
                *reinterpret_cast<uint2v*>(orow + 8 * rr + 4 * hi) = u;
            }
            {
                uint2v u;
                u[0] = cvtpk_bf16(o1[4 * rr] * inv, o1[4 * rr + 1] * inv);
                u[1] = cvtpk_bf16(o1[4 * rr + 2] * inv, o1[4 * rr + 3] * inv);
                *reinterpret_cast<uint2v*>(orow + 32 + 8 * rr + 4 * hi) = u;
            }
        }
    } else {
        // partial write: unnormalized bf16 O + (m, s) per row
        const int g = h * 36 + gbase + sl;
        const int row = w * 32 + lq;                      // 0..255 within chunk
        __hip_bfloat16* pb = Opart + ((size_t)g * 256 + row) * 64;
#pragma unroll
        for (int rr = 0; rr < 4; ++rr) {
            {
                uint2v u;
                u[0] = cvtpk_bf16(o0[4 * rr], o0[4 * rr + 1]);
                u[1] = cvtpk_bf16(o0[4 * rr + 2], o0[4 * rr + 3]);
                *reinterpret_cast<uint2v*>(pb + 8 * rr + 4 * hi) = u;
            }
            {
                uint2v u;
                u[0] = cvtpk_bf16(o1[4 * rr], o1[4 * rr + 1]);
                u[1] = cvtpk_bf16(o1[4 * rr + 2], o1[4 * rr + 3]);
                *reinterpret_cast<uint2v*>(pb + 32 + 8 * rr + 4 * hi) = u;
            }
        }
        if (hi == 0) {
            const size_t mi = (size_t)g * 256 + row;
            ms[mi * 2] = m_run;
            ms[mi * 2 + 1] = s_run;
        }
    }
}

// ---------------------------------------------------------------------------
// Merge split-KV partials for qc >= 1. grid (7 qc, 8 rowgroup, 32 h), 256 thr.
// ---------------------------------------------------------------------------
__device__ __constant__ int kCum2[8] = {0, 1, 3, 6, 10, 15, 21, 28};

__global__ __launch_bounds__(256) void attn_merge(const __hip_bfloat16* __restrict__ Opart,
                                                  const float* __restrict__ ms,
                                                  __hip_bfloat16* __restrict__ O) {
    const int qc = 1 + blockIdx.x;                    // 1..7
    const int h = blockIdx.z;
    const int tid = threadIdx.x;
    const int row = blockIdx.y * 32 + (tid >> 3);     // 0..255
    const int dv0 = (tid & 7) * 8;
    const int ns = qc + 1;                            // 2..8
    const int g0 = h * 36 + kCum2[qc];

    float mv[8], sv[8];
    float M = -__builtin_inff();
#pragma unroll
    for (int s = 0; s < 8; ++s) {
        if (s < ns) {
            const size_t mi = (size_t)(g0 + s) * 256 + row;
            mv[s] = ms[mi * 2];
            sv[s] = ms[mi * 2 + 1];
            M = fmaxf(M, mv[s]);
        }
    }
    float S = 0.f;
    float acc[8];
#pragma unroll
    for (int j = 0; j < 8; ++j) acc[j] = 0.f;
#pragma unroll
    for (int s = 0; s < 8; ++s) {
        if (s < ns) {
            const float wgt = exp2f(mv[s] - M);
            S += wgt * sv[s];
            const bf16x8 v = *reinterpret_cast<const bf16x8*>(
                &Opart[((size_t)(g0 + s) * 256 + row) * 64 + dv0]);
#pragma unroll
            for (int j = 0; j < 8; ++j) acc[j] += wgt * (float)v[j];
        }
    }
    const float inv = 1.0f / S;
    uint4v u;
    u[0] = cvtpk_bf16(acc[0] * inv, acc[1] * inv);
    u[1] = cvtpk_bf16(acc[2] * inv, acc[3] * inv);
    u[2] = cvtpk_bf16(acc[4] * inv, acc[5] * inv);
    u[3] = cvtpk_bf16(acc[6] * inv, acc[7] * inv);
    *reinterpret_cast<uint4v*>(&O[(size_t)(qc * 256 + row) * D_MODEL + h * HEAD_DIM + dv0]) = u;
}

// ---------------------------------------------------------------------------
// Launch
// ---------------------------------------------------------------------------
extern "C" void kernel_launch(void* const* d_in, const int* in_sizes, int n_in,
                              void* d_out, int out_size, void* d_ws, size_t ws_size,
                              hipStream_t stream) {
    const float* x  = (const float*)d_in[0];
    const float* wq = (const float*)d_in[1];
    const float* wk = (const float*)d_in[2];
    const float* wv = (const float*)d_in[3];
    const float* wo = (const float*)d_in[4];
    const float* fc = (const float*)d_in[5];
    const float* fs = (const float*)d_in[6];
    float* out = (float*)d_out;

    char* ws = (char*)d_ws;
    __hip_bfloat16* wqkvT = (__hip_bfloat16*)(ws);                 // [3072][2048] bf16, 12 MiB
    __hip_bfloat16* woT   = (__hip_bfloat16*)(ws + (12u << 20));   // [2048][2048], 8 MiB
    __hip_bfloat16* attnb = (__hip_bfloat16*)(ws + (20u << 20));   // [2048][2048], 8 MiB
    __hip_bfloat16* xb    = (__hip_bfloat16*)(ws + (28u << 20));   // [2048][2048], 8 MiB
    __hip_bfloat16* QKV   = (__hip_bfloat16*)(ws + (36u << 20));   // [2048][3072], 12 MiB
    __hip_bfloat16* Vt    = (__hip_bfloat16*)(ws + (48u << 20));   // [512][2048], 2 MiB
    float*          msb   = (float*)(ws + (50u << 20));            // 1152*256*2 f32, 2.4 MiB
    __hip_bfloat16* Opart = (__hip_bfloat16*)(ws + (53u << 20));   // 1152*256*64 bf16, 38 MiB

    const int split = (ws_size >= (96ull << 20)) ? 1 : 0;

    const dim3 tb(32, 8);
    transpose_convert<<<dim3(D_MODEL / 32, D_MODEL / 32), tb, 0, stream>>>(wq, wqkvT, D_MODEL, D_MODEL);
    transpose_convert<<<dim3(KV_DIM / 32, D_MODEL / 32), tb, 0, stream>>>(wk, wqkvT + (size_t)D_MODEL * D_MODEL, D_MODEL, KV_DIM);
    transpose_convert<<<dim3(KV_DIM / 32, D_MODEL / 32), tb, 0, stream>>>(wv, wqkvT + (size_t)(D_MODEL + KV_DIM) * D_MODEL, D_MODEL, KV_DIM);
    transpose_convert<<<dim3(D_MODEL / 32, D_MODEL / 32), tb, 0, stream>>>(wo, woT, D_MODEL, D_MODEL);
    convert_bf16<<<(S_LEN * D_MODEL) / (256 * 8), 256, 0, stream>>>(x, xb);

    // fused QKV projection: [2048][3072]  (1D grid 384 blocks, T1 swizzle)
    gemm_bt<__hip_bfloat16><<<dim3((QKV_N / 128) * (S_LEN / 128)), 256, 0, stream>>>(xb, wqkvT, QKV, S_LEN, QKV_N, D_MODEL);

    // fused RoPE on Q (scaled by 1/8*log2e) and K
    rope_qk<<<(S_LEN * (N_HEADS + N_KV) * 32) / 256, 256, 0, stream>>>(QKV, fc, fs);

    // V transpose to [hkv*64+d][s]
    transpose_v<<<dim3(S_LEN / 64, N_KV), 256, 0, stream>>>(QKV, Vt);

    // causal GQA flash attention (8 waves, 256 q-rows/block, deep split-KV)
    if (split) {
        attn_kernel<<<dim3(36, N_HEADS), 512, 0, stream>>>(QKV, Vt, attnb, Opart, msb, 1);
        attn_merge<<<dim3(7, 8, N_HEADS), 256, 0, stream>>>(Opart, msb, attnb);
    } else {
        attn_kernel<<<dim3(8, N_HEADS), 512, 0, stream>>>(QKV, Vt, attnb, Opart, msb, 0);
    }

    // output projection -> f32 (1D grid 256 blocks, T1 swizzle)
    gemm_bt<float><<<dim3((D_MODEL / 128) * (S_LEN / 128)), 256, 0, stream>>>(attnb, woT, out, S_LEN, D_MODEL, D_MODEL);

    (void)in_sizes; (void)n_in; (void)out_size;
}

// Round 16
// 148.716 us; speedup vs baseline: 1.1761x; 1.1761x over previous
//
#include <hip/hip_runtime.h>
#include <hip/hip_bf16.h>

#define S_LEN 2048
#define D_MODEL 2048
#define N_HEADS 32
#define N_KV 8
#define HEAD_DIM 64
#define KV_DIM (N_KV * HEAD_DIM)    // 512
#define QKV_N (D_MODEL + 2 * KV_DIM) // 3072

typedef __bf16 bf16_t;
typedef __attribute__((ext_vector_type(8))) __bf16 bf16x8;
typedef __attribute__((ext_vector_type(4))) float f32x4;
typedef __attribute__((ext_vector_type(16))) float f32x16;
typedef __attribute__((ext_vector_type(4))) unsigned int uint4v;
typedef __attribute__((ext_vector_type(2))) unsigned int uint2v;

// ---------------------------------------------------------------------------
// async global->LDS 16B copy. LDS dest must be wave-uniform base + lane*16.
// ---------------------------------------------------------------------------
__device__ __forceinline__ void gload_lds16(const void* g, void* l) {
    __builtin_amdgcn_global_load_lds(
        (const __attribute__((address_space(1))) unsigned char*)g,
        (__attribute__((address_space(3))) unsigned char*)l,
        16, 0, 0);
}

// ---------------------------------------------------------------------------
// Fused preprocessing: ONE launch does all four weight transposes
// (f32 [R][C] -> bf16 [C][R]) + the x f32->bf16 convert. Block ranges:
//   [0,4096)      wq -> wqkvT[0..2048)          (64x64 tiles)
//   [4096,5120)   wk -> wqkvT[2048..2560)       (16x64)
//   [5120,6144)   wv -> wqkvT[2560..3072)       (16x64)
//   [6144,10240)  wo -> woT                     (64x64)
//   [10240,12288) x  -> xb  (8 elems/thread)
// Branch is block-uniform -> __syncthreads in transpose path is safe.
// ---------------------------------------------------------------------------
__global__ __launch_bounds__(256) void prep_kernel(const float* __restrict__ x,
                                                   const float* __restrict__ wq,
                                                   const float* __restrict__ wk,
                                                   const float* __restrict__ wv,
                                                   const float* __restrict__ wo,
                                                   __hip_bfloat16* __restrict__ wqkvT,
                                                   __hip_bfloat16* __restrict__ woT,
                                                   __hip_bfloat16* __restrict__ xb) {
    __shared__ float tile[32][33];
    const int bid = (int)blockIdx.x;
    const int tid = threadIdx.x;
    if (bid < 10240) {
        const float* src;
        __hip_bfloat16* dst;
        int C, gx, gy;
        if (bid < 4096)      { src = wq; dst = wqkvT; C = D_MODEL; gx = bid & 63; gy = bid >> 6; }
        else if (bid < 5120) { src = wk; dst = wqkvT + (size_t)D_MODEL * D_MODEL; C = KV_DIM; gx = (bid - 4096) & 15; gy = (bid - 4096) >> 4; }
        else if (bid < 6144) { src = wv; dst = wqkvT + (size_t)(D_MODEL + KV_DIM) * D_MODEL; C = KV_DIM; gx = (bid - 5120) & 15; gy = (bid - 5120) >> 4; }
        else                 { src = wo; dst = woT; C = D_MODEL; gx = (bid - 6144) & 63; gy = (bid - 6144) >> 6; }
        const int R = D_MODEL;
        const int bx = gx * 32, by = gy * 32;
        const int tx = tid & 31, ty = tid >> 5;   // 0..31, 0..7
#pragma unroll
        for (int i = 0; i < 32; i += 8)
            tile[ty + i][tx] = src[(size_t)(by + ty + i) * C + bx + tx];
        __syncthreads();
#pragma unroll
        for (int i = 0; i < 32; i += 8)
            dst[(size_t)(bx + ty + i) * R + by + tx] = __float2bfloat16(tile[tx][ty + i]);
    } else {
        const int i = ((bid - 10240) * 256 + tid) * 8;
        const float4 a = *reinterpret_cast<const float4*>(x + i);
        const float4 b = *reinterpret_cast<const float4*>(x + i + 4);
        bf16x8 r;
        r[0] = (__bf16)a.x; r[1] = (__bf16)a.y; r[2] = (__bf16)a.z; r[3] = (__bf16)a.w;
        r[4] = (__bf16)b.x; r[5] = (__bf16)b.y; r[6] = (__bf16)b.z; r[7] = (__bf16)b.w;
        *reinterpret_cast<bf16x8*>(xb + i) = r;
    }
}

// ---------------------------------------------------------------------------
// Fused RoPE (Q scaled by 1/8*log2e, K unscaled) + V transpose. Disjoint
// QKV column ranges (rope: [0,2560), transpose_v reads [2560,3072)) ->
// race-free fusion. Blocks [0,10240) rope; [10240,10496) V-transpose.
// ---------------------------------------------------------------------------
__global__ __launch_bounds__(256) void rope_v_kernel(__hip_bfloat16* __restrict__ QKV,
                                                     const float* __restrict__ cos_t,
                                                     const float* __restrict__ sin_t,
                                                     __hip_bfloat16* __restrict__ Vt) {
    __shared__ __align__(16) __bf16 vtile[64][72];
    const int bid = (int)blockIdx.x;
    const int tid = threadIdx.x;
    if (bid < 10240) {
        const int idx = bid * 256 + tid;          // S * 40 * 32 total
        const int i = idx & 31;
        const int hh = (idx >> 5) % (N_HEADS + N_KV);
        const int s = idx / (32 * (N_HEADS + N_KV));
        const float c = cos_t[s * 32 + i];
        const float sn = sin_t[s * 32 + i];
        int col; float scale;
        if (hh < N_HEADS) { col = hh * HEAD_DIM + 2 * i; scale = 0.125f * 1.44269504f; }
        else { col = D_MODEL + (hh - N_HEADS) * HEAD_DIM + 2 * i; scale = 1.0f; }
        __hip_bfloat16* p = &QKV[(size_t)s * QKV_N + col];
        const float re = __bfloat162float(p[0]);
        const float im = __bfloat162float(p[1]);
        p[0] = __float2bfloat16((re * c - im * sn) * scale);
        p[1] = __float2bfloat16((re * sn + im * c) * scale);
    } else {
        const int vb = bid - 10240;               // 0..255
        const int s0 = (vb & 31) * 64;
        const int hkv = vb >> 5;
        {
            const int r = tid >> 2;
            const int c0 = (tid & 3) * 16;
            const __hip_bfloat16* src = QKV + (size_t)(s0 + r) * QKV_N + D_MODEL + KV_DIM + hkv * HEAD_DIM + c0;
            *reinterpret_cast<bf16x8*>(&vtile[r][c0]) = *reinterpret_cast<const bf16x8*>(src);
            *reinterpret_cast<bf16x8*>(&vtile[r][c0 + 8]) = *reinterpret_cast<const bf16x8*>(src + 8);
        }
        __syncthreads();
        {
            const int d = tid >> 2;
            const int sc = (tid & 3) * 16;
            bf16x8 o0, o1;
#pragma unroll
            for (int j = 0; j < 8; ++j) { o0[j] = vtile[sc + j][d]; o1[j] = vtile[sc + 8 + j][d]; }
            __hip_bfloat16* dst = Vt + (size_t)(hkv * HEAD_DIM + d) * S_LEN + s0 + sc;
            *reinterpret_cast<bf16x8*>(dst) = o0;
            *reinterpret_cast<bf16x8*>(dst + 8) = o1;
        }
    }
}

// ---------------------------------------------------------------------------
// GEMM (reverted to R11's proven best): 128x128 tile, BK=64, 4 waves,
// 2-phase prefetch (dbuf LDS, stage(t+1) before compute(t), one
// vmcnt(0)+s_barrier per K-step). Full (row&7) XOR chunk swizzle.
// Three deeper-pipeline attempts (R9/R12/R14) all lost to this; accepted
// as this structure's ceiling.
// ---------------------------------------------------------------------------
__device__ inline void storeC(__hip_bfloat16* p, float v) { *p = __float2bfloat16(v); }
__device__ inline void storeC(float* p, float v) { *p = v; }

template <typename OutT>
__global__ __launch_bounds__(256) void gemm_bt(const __hip_bfloat16* __restrict__ A,
                                               const __hip_bfloat16* __restrict__ Bt,
                                               OutT* __restrict__ C,
                                               int M, int N, int K) {
    __shared__ __align__(16) __bf16 As[2][128 * 64];   // 16 KB x2
    __shared__ __align__(16) __bf16 Bs[2][128 * 64];   // 16 KB x2
    const int tid = threadIdx.x;
    const int w = tid >> 6, l = tid & 63;
    const int wr = w >> 1, wc = w & 1;
    const int l4 = l >> 4, l15 = l & 15;
    const int bm = blockIdx.y * 128, bn = blockIdx.x * 128;

    f32x4 acc[4][4];
#pragma unroll
    for (int i = 0; i < 4; ++i)
#pragma unroll
        for (int j = 0; j < 4; ++j) acc[i][j] = (f32x4){0.f, 0.f, 0.f, 0.f};

    // stage: 1024 16B-chunks per array (8 chunks/row of 64 cols); 4/thread
    auto stage = [&](int buf, int k0) {
#pragma unroll
        for (int p = 0; p < 4; ++p) {
            const int chunk = p * 256 + tid;
            const int row = chunk >> 3;
            const int cs = (chunk & 7) ^ (row & 7);   // pre-swizzled source chunk
            gload_lds16(&A[(size_t)(bm + row) * K + k0 + cs * 8], &As[buf][chunk * 8]);
            gload_lds16(&Bt[(size_t)(bn + row) * K + k0 + cs * 8], &Bs[buf][chunk * 8]);
        }
    };

    const int nk = K >> 6;   // BK=64 steps
    stage(0, 0);
    asm volatile("s_waitcnt vmcnt(0)" ::: "memory");
    __builtin_amdgcn_s_barrier();

#pragma unroll 2
    for (int kt = 0; kt < nk; ++kt) {
        const int cur = kt & 1;
        if (kt + 1 < nk) stage(cur ^ 1, (kt + 1) * 64);   // prefetch next tile
#pragma unroll
        for (int ks = 0; ks < 2; ++ks) {
            bf16x8 a[4], b[4];
#pragma unroll
            for (int mi = 0; mi < 4; ++mi) {
                const int rr = wr * 64 + mi * 16 + l15;
                a[mi] = *reinterpret_cast<const bf16x8*>(
                    &As[cur][rr * 64 + (((ks * 4 + l4) ^ (rr & 7))) * 8]);
            }
#pragma unroll
            for (int ni = 0; ni < 4; ++ni) {
                const int rr = wc * 64 + ni * 16 + l15;
                b[ni] = *reinterpret_cast<const bf16x8*>(
                    &Bs[cur][rr * 64 + (((ks * 4 + l4) ^ (rr & 7))) * 8]);
            }
#pragma unroll
            for (int mi = 0; mi < 4; ++mi)
#pragma unroll
                for (int ni = 0; ni < 4; ++ni)
                    acc[mi][ni] = __builtin_amdgcn_mfma_f32_16x16x32_bf16(a[mi], b[ni], acc[mi][ni], 0, 0, 0);
        }
        // publish next tile (prefetch latency hidden under 32 MFMAs) + quiesce
        asm volatile("s_waitcnt vmcnt(0)" ::: "memory");
        __builtin_amdgcn_s_barrier();
    }
#pragma unroll
    for (int mi = 0; mi < 4; ++mi)
#pragma unroll
        for (int ni = 0; ni < 4; ++ni)
#pragma unroll
            for (int r = 0; r < 4; ++r) {
                const int row = bm + wr * 64 + mi * 16 + l4 * 4 + r;
                const int col = bn + wc * 64 + ni * 16 + l15;
                storeC(&C[(size_t)row * N + col], acc[mi][ni][r]);
            }
}

// ---------------------------------------------------------------------------
// permlane32_swap: swaps x[hi lanes] with y[lo lanes].
// VALU-pipe (1.20x vs ds_bpermute, m255). Fallback emulation via shfl.
// ---------------------------------------------------------------------------
#if __has_builtin(__builtin_amdgcn_permlane32_swap)
__device__ __forceinline__ void plswap(unsigned& x, unsigned& y, int) {
    uint2v r = __builtin_amdgcn_permlane32_swap(x, y, false, false);
    x = r[0]; y = r[1];
}
#else
__device__ __forceinline__ void plswap(unsigned& x, unsigned& y, int hi) {
    const unsigned px = __shfl_xor(x, 32, 64);
    const unsigned py = __shfl_xor(y, 32, 64);
    const unsigned nx = hi ? py : x;
    const unsigned ny = hi ? y : px;
    x = nx; y = ny;
}
#endif

__device__ __forceinline__ unsigned cvtpk_bf16(float lo, float hi) {
    unsigned w;
    asm("v_cvt_pk_bf16_f32 %0, %1, %2" : "=v"(w) : "v"(lo), "v"(hi));
    return w;
}
__device__ __forceinline__ float swap_max(float v, int hi) {
    unsigned x = __builtin_bit_cast(unsigned, v), y = x;
    plswap(x, y, hi);
    return fmaxf(__builtin_bit_cast(float, x), __builtin_bit_cast(float, y));
}
__device__ __forceinline__ float swap_add(float v, int hi) {
    unsigned x = __builtin_bit_cast(unsigned, v), y = x;
    plswap(x, y, hi);
    return __builtin_bit_cast(float, x) + __builtin_bit_cast(float, y);
}
// Build PV B-fragment for one 16-kv k-step from 8 own p-values s[R0..R0+7].
template <int R0>
__device__ __forceinline__ bf16x8 build_pfrag(const f32x16& s, int hi) {
    unsigned A0 = cvtpk_bf16(s[R0 + 0], s[R0 + 1]);
    unsigned A1 = cvtpk_bf16(s[R0 + 2], s[R0 + 3]);
    unsigned B0 = cvtpk_bf16(s[R0 + 4], s[R0 + 5]);
    unsigned B1 = cvtpk_bf16(s[R0 + 6], s[R0 + 7]);
    plswap(A0, B0, hi);
    plswap(A1, B1, hi);
    uint4v u; u[0] = A0; u[1] = A1; u[2] = B0; u[3] = B1;
    return __builtin_bit_cast(bf16x8, u);
}

// ---------------------------------------------------------------------------
// Flash attention v11 (unchanged): deep split-KV, slices of 4 tiles
// (256 kv) -> 36 slices/head = 1152 blocks. ns(qc)=qc+1.
// ---------------------------------------------------------------------------
__global__ __launch_bounds__(512) void attn_kernel(const __hip_bfloat16* __restrict__ QKV,
                                                   const __hip_bfloat16* __restrict__ Vt,
                                                   __hip_bfloat16* __restrict__ O,
                                                   __hip_bfloat16* __restrict__ Opart,
                                                   float* __restrict__ ms,
                                                   int split) {
    const int h = blockIdx.y;
    const int hkv = h >> 2;
    int qc = 0, sl = 0, gbase = 0, ns = 1;
    if (!split) {
        qc = 7 - (int)blockIdx.x;
    } else {
        const int x = (int)blockIdx.x;      // 0..35
        int cum = 0;
#pragma unroll
        for (int q = 0; q < 8; ++q) {
            const int n = q + 1;
            if (x >= cum && x < cum + n) { qc = q; sl = x - cum; gbase = cum; }
            cum += n;
        }
        ns = qc + 1;
    }
    const int ntf = 4 * (qc + 1);
    const int t0 = split ? sl * 4 : 0;
    const int t1 = split ? min(t0 + 4, ntf) : ntf;

    const int tid = threadIdx.x;
    const int w = tid >> 6, l = tid & 63;
    const int lq = l & 31, hi = l >> 5;
    const int q0w = qc * 256 + w * 32;
    const int qlane = q0w + lq;

    __shared__ __align__(16) __bf16 Ks[2][64 * 64];  // [kv][d] swizzled
    __shared__ __align__(16) __bf16 Vs[2][64 * 64];  // [d][kv] swizzled

    const __hip_bfloat16* Kg = QKV + D_MODEL + hkv * HEAD_DIM;       // [s][QKV_N]
    const __hip_bfloat16* Vg = Vt + (size_t)hkv * HEAD_DIM * S_LEN;  // [d][S]

    auto stage = [&](int buf, int kv0) {
        const int chunk = tid;                    // 0..511
        const int r = chunk >> 3;                 // row 0..63
        const int cs = (chunk & 7) ^ (r & 7);     // pre-swizzled source chunk
        gload_lds16(&Kg[(size_t)(kv0 + r) * QKV_N + cs * 8], &Ks[buf][chunk * 8]);
        gload_lds16(&Vg[(size_t)r * S_LEN + kv0 + cs * 8], &Vs[buf][chunk * 8]);
    };

    // Q as B-operand: lane holds Q[qlane][16f + 8*hi + e]
    bf16x8 qf[4];
#pragma unroll
    for (int f = 0; f < 4; ++f)
        qf[f] = *reinterpret_cast<const bf16x8*>(
            &QKV[(size_t)qlane * QKV_N + h * HEAD_DIM + 16 * f + 8 * hi]);

    f32x16 o0, o1;
#pragma unroll
    for (int r = 0; r < 16; ++r) { o0[r] = 0.f; o1[r] = 0.f; }
    float m_run = -__builtin_inff(), s_run = 0.f;

    stage(0, t0 * 64);

#pragma unroll 1
    for (int t = t0; t < t1; ++t) {
        __syncthreads();                       // tile t staged (vmcnt drained)
        if (t + 1 < t1) stage((t + 1 - t0) & 1, (t + 1) * 64);
        const int kv0 = t * 64;
        if (kv0 <= q0w + 31) {                 // wave-uniform: skip fully-masked
            const __bf16* Kb = Ks[(t - t0) & 1];
            const __bf16* Vb = Vs[(t - t0) & 1];

            // S^T = K · Q^T  (two 32-kv sub-tiles)
            f32x16 s0, s1;
#pragma unroll
            for (int r = 0; r < 16; ++r) { s0[r] = 0.f; s1[r] = 0.f; }
            __builtin_amdgcn_s_setprio(1);
#pragma unroll
            for (int f = 0; f < 4; ++f) {
                const int rr0 = lq;
                const int rr1 = 32 + lq;
                const bf16x8 ka0 = *reinterpret_cast<const bf16x8*>(
                    &Kb[rr0 * 64 + (((2 * f + hi) ^ (rr0 & 7))) * 8]);
                const bf16x8 ka1 = *reinterpret_cast<const bf16x8*>(
                    &Kb[rr1 * 64 + (((2 * f + hi) ^ (rr1 & 7))) * 8]);
                s0 = __builtin_amdgcn_mfma_f32_32x32x16_bf16(ka0, qf[f], s0, 0, 0, 0);
                s1 = __builtin_amdgcn_mfma_f32_32x32x16_bf16(ka1, qf[f], s1, 0, 0, 0);
            }
            __builtin_amdgcn_s_setprio(0);
            // causal mask (only tiles crossing the diagonal)
            if (kv0 + 63 > q0w) {
#pragma unroll
                for (int r = 0; r < 16; ++r) {
                    const int kvb = (r & 3) + 8 * (r >> 2) + 4 * hi;
                    if (kv0 + kvb > qlane) s0[r] = -__builtin_inff();
                    if (kv0 + 32 + kvb > qlane) s1[r] = -__builtin_inff();
                }
            }
            // row max: tree over own 32 regs, then partner exchange
            float ta = fmaxf(s0[0], s1[0]), tb = fmaxf(s0[1], s1[1]);
            float tc = fmaxf(s0[2], s1[2]), td = fmaxf(s0[3], s1[3]);
#pragma unroll
            for (int r = 4; r < 16; r += 4) {
                ta = fmaxf(ta, fmaxf(s0[r], s1[r]));
                tb = fmaxf(tb, fmaxf(s0[r + 1], s1[r + 1]));
                tc = fmaxf(tc, fmaxf(s0[r + 2], s1[r + 2]));
                td = fmaxf(td, fmaxf(s0[r + 3], s1[r + 3]));
            }
            const float m_row = swap_max(fmaxf(fmaxf(ta, tb), fmaxf(tc, td)), hi);

            // defer-max: skip rescale when max grew by <= 8 (exp2 domain)
            if (!__all(m_row <= m_run + 8.0f)) {
                const float mnew = fmaxf(m_run, m_row);
                const float corr = exp2f(m_run - mnew);
                m_run = mnew;
                s_run *= corr;
#pragma unroll
                for (int r = 0; r < 16; ++r) { o0[r] *= corr; o1[r] *= corr; }
            }
            // P = exp2(S - m_run)
#pragma unroll
            for (int r = 0; r < 16; ++r) {
                s0[r] = exp2f(s0[r] - m_run);
                s1[r] = exp2f(s1[r] - m_run);
            }
            // row sum
            float ua = s0[0] + s1[0], ub = s0[1] + s1[1];
            float uc = s0[2] + s1[2], ud = s0[3] + s1[3];
#pragma unroll
            for (int r = 4; r < 16; r += 4) {
                ua += s0[r] + s1[r];
                ub += s0[r + 1] + s1[r + 1];
                uc += s0[r + 2] + s1[r + 2];
                ud += s0[r + 3] + s1[r + 3];
            }
            s_run += swap_add((ua + ub) + (uc + ud), hi);

            // P fragments (k-steps of 16 kv)
            bf16x8 pa[4];
            pa[0] = build_pfrag<0>(s0, hi);
            pa[1] = build_pfrag<8>(s0, hi);
            pa[2] = build_pfrag<0>(s1, hi);
            pa[3] = build_pfrag<8>(s1, hi);

            // O^T += V^T · P^T
            __builtin_amdgcn_s_setprio(1);
#pragma unroll
            for (int ks = 0; ks < 4; ++ks) {
                const int rv0 = lq;
                const int rv1 = 32 + lq;
                const bf16x8 va0 = *reinterpret_cast<const bf16x8*>(
                    &Vb[rv0 * 64 + (((2 * ks + hi) ^ (rv0 & 7))) * 8]);
                const bf16x8 va1 = *reinterpret_cast<const bf16x8*>(
                    &Vb[rv1 * 64 + (((2 * ks + hi) ^ (rv1 & 7))) * 8]);
                o0 = __builtin_amdgcn_mfma_f32_32x32x16_bf16(va0, pa[ks], o0, 0, 0, 0);
                o1 = __builtin_amdgcn_mfma_f32_32x32x16_bf16(va1, pa[ks], o1, 0, 0, 0);
            }
            __builtin_amdgcn_s_setprio(0);
        }
    }

    if (ns == 1) {
        // direct normalized write: O^T[dv][q] -> O[q][h*64+dv]
        const float inv = 1.0f / s_run;
        __hip_bfloat16* orow = O + (size_t)qlane * D_MODEL + h * HEAD_DIM;
#pragma unroll
        for (int rr = 0; rr < 4; ++rr) {
            {
                uint2v u;
                u[0] = cvtpk_bf16(o0[4 * rr] * inv, o0[4 * rr + 1] * inv);
                u[1] = cvtpk_bf16(o0[4 * rr + 2] * inv, o0[4 * rr + 3] * inv);
                *reinterpret_cast<uint2v*>(orow + 8 * rr + 4 * hi) = u;
            }
            {
                uint2v u;
                u[0] = cvtpk_bf16(o1[4 * rr] * inv, o1[4 * rr + 1] * inv);
                u[1] = cvtpk_bf16(o1[4 * rr + 2] * inv, o1[4 * rr + 3] * inv);
                *reinterpret_cast<uint2v*>(orow + 32 + 8 * rr + 4 * hi) = u;
            }
        }
    } else {
        // partial write: unnormalized bf16 O + (m, s) per row
        const int g = h * 36 + gbase + sl;
        const int row = w * 32 + lq;                      // 0..255 within chunk
        __hip_bfloat16* pb = Opart + ((size_t)g * 256 + row) * 64;
#pragma unroll
        for (int rr = 0; rr < 4; ++rr) {
            {
                uint2v u;
                u[0] = cvtpk_bf16(o0[4 * rr], o0[4 * rr + 1]);
                u[1] = cvtpk_bf16(o0[4 * rr + 2], o0[4 * rr + 3]);
                *reinterpret_cast<uint2v*>(pb + 8 * rr + 4 * hi) = u;
            }
            {
                uint2v u;
                u[0] = cvtpk_bf16(o1[4 * rr], o1[4 * rr + 1]);
                u[1] = cvtpk_bf16(o1[4 * rr + 2], o1[4 * rr + 3]);
                *reinterpret_cast<uint2v*>(pb + 32 + 8 * rr + 4 * hi) = u;
            }
        }
        if (hi == 0) {
            const size_t mi = (size_t)g * 256 + row;
            ms[mi * 2] = m_run;
            ms[mi * 2 + 1] = s_run;
        }
    }
}

// ---------------------------------------------------------------------------
// Merge split-KV partials for qc >= 1. grid (7 qc, 8 rowgroup, 32 h), 256 thr.
// ---------------------------------------------------------------------------
__device__ __constant__ int kCum2[8] = {0, 1, 3, 6, 10, 15, 21, 28};

__global__ __launch_bounds__(256) void attn_merge(const __hip_bfloat16* __restrict__ Opart,
                                                  const float* __restrict__ ms,
                                                  __hip_bfloat16* __restrict__ O) {
    const int qc = 1 + blockIdx.x;                    // 1..7
    const int h = blockIdx.z;
    const int tid = threadIdx.x;
    const int row = blockIdx.y * 32 + (tid >> 3);     // 0..255
    const int dv0 = (tid & 7) * 8;
    const int ns = qc + 1;                            // 2..8
    const int g0 = h * 36 + kCum2[qc];

    float mv[8], sv[8];
    float M = -__builtin_inff();
#pragma unroll
    for (int s = 0; s < 8; ++s) {
        if (s < ns) {
            const size_t mi = (size_t)(g0 + s) * 256 + row;
            mv[s] = ms[mi * 2];
            sv[s] = ms[mi * 2 + 1];
            M = fmaxf(M, mv[s]);
        }
    }
    float S = 0.f;
    float acc[8];
#pragma unroll
    for (int j = 0; j < 8; ++j) acc[j] = 0.f;
#pragma unroll
    for (int s = 0; s < 8; ++s) {
        if (s < ns) {
            const float wgt = exp2f(mv[s] - M);
            S += wgt * sv[s];
            const bf16x8 v = *reinterpret_cast<const bf16x8*>(
                &Opart[((size_t)(g0 + s) * 256 + row) * 64 + dv0]);
#pragma unroll
            for (int j = 0; j < 8; ++j) acc[j] += wgt * (float)v[j];
        }
    }
    const float inv = 1.0f / S;
    uint4v u;
    u[0] = cvtpk_bf16(acc[0] * inv, acc[1] * inv);
    u[1] = cvtpk_bf16(acc[2] * inv, acc[3] * inv);
    u[2] = cvtpk_bf16(acc[4] * inv, acc[5] * inv);
    u[3] = cvtpk_bf16(acc[6] * inv, acc[7] * inv);
    *reinterpret_cast<uint4v*>(&O[(size_t)(qc * 256 + row) * D_MODEL + h * HEAD_DIM + dv0]) = u;
}

// ---------------------------------------------------------------------------
// Launch: 6 dispatches (was 10).
// ---------------------------------------------------------------------------
extern "C" void kernel_launch(void* const* d_in, const int* in_sizes, int n_in,
                              void* d_out, int out_size, void* d_ws, size_t ws_size,
                              hipStream_t stream) {
    const float* x  = (const float*)d_in[0];
    const float* wq = (const float*)d_in[1];
    const float* wk = (const float*)d_in[2];
    const float* wv = (const float*)d_in[3];
    const float* wo = (const float*)d_in[4];
    const float* fc = (const float*)d_in[5];
    const float* fs = (const float*)d_in[6];
    float* out = (float*)d_out;

    char* ws = (char*)d_ws;
    __hip_bfloat16* wqkvT = (__hip_bfloat16*)(ws);                 // [3072][2048] bf16, 12 MiB
    __hip_bfloat16* woT   = (__hip_bfloat16*)(ws + (12u << 20));   // [2048][2048], 8 MiB
    __hip_bfloat16* attnb = (__hip_bfloat16*)(ws + (20u << 20));   // [2048][2048], 8 MiB
    __hip_bfloat16* xb    = (__hip_bfloat16*)(ws + (28u << 20));   // [2048][2048], 8 MiB
    __hip_bfloat16* QKV   = (__hip_bfloat16*)(ws + (36u << 20));   // [2048][3072], 12 MiB
    __hip_bfloat16* Vt    = (__hip_bfloat16*)(ws + (48u << 20));   // [512][2048], 2 MiB
    float*          msb   = (float*)(ws + (50u << 20));            // 1152*256*2 f32, 2.4 MiB
    __hip_bfloat16* Opart = (__hip_bfloat16*)(ws + (53u << 20));   // 1152*256*64 bf16, 38 MiB

    const int split = (ws_size >= (96ull << 20)) ? 1 : 0;

    // fused preprocessing: all weight transposes + x convert (1 launch)
    prep_kernel<<<12288, 256, 0, stream>>>(x, wq, wk, wv, wo, wqkvT, woT, xb);

    // fused QKV projection: [2048][3072]
    gemm_bt<__hip_bfloat16><<<dim3(QKV_N / 128, S_LEN / 128), 256, 0, stream>>>(xb, wqkvT, QKV, S_LEN, QKV_N, D_MODEL);

    // fused RoPE (Q,K) + V transpose (1 launch)
    rope_v_kernel<<<10496, 256, 0, stream>>>(QKV, fc, fs, Vt);

    // causal GQA flash attention (8 waves, 256 q-rows/block, deep split-KV)
    if (split) {
        attn_kernel<<<dim3(36, N_HEADS), 512, 0, stream>>>(QKV, Vt, attnb, Opart, msb, 1);
        attn_merge<<<dim3(7, 8, N_HEADS), 256, 0, stream>>>(Opart, msb, attnb);
    } else {
        attn_kernel<<<dim3(8, N_HEADS), 512, 0, stream>>>(QKV, Vt, attnb, Opart, msb, 0);
    }

    // output projection -> f32
    gemm_bt<float><<<dim3(D_MODEL / 128, S_LEN / 128), 256, 0, stream>>>(attnb, woT, out, S_LEN, D_MODEL, D_MODEL);

    (void)in_sizes; (void)n_in; (void)out_size;
}

// Round 17
// 142.455 us; speedup vs baseline: 1.2278x; 1.0440x over previous
//
#include <hip/hip_runtime.h>
#include <hip/hip_bf16.h>

#define S_LEN 2048
#define D_MODEL 2048
#define N_HEADS 32
#define N_KV 8
#define HEAD_DIM 64
#define KV_DIM (N_KV * HEAD_DIM)    // 512
#define QKV_N (D_MODEL + 2 * KV_DIM) // 3072

typedef __bf16 bf16_t;
typedef __attribute__((ext_vector_type(8))) __bf16 bf16x8;
typedef __attribute__((ext_vector_type(4))) float f32x4;
typedef __attribute__((ext_vector_type(16))) float f32x16;
typedef __attribute__((ext_vector_type(4))) unsigned int uint4v;
typedef __attribute__((ext_vector_type(2))) unsigned int uint2v;

// ---------------------------------------------------------------------------
// async global->LDS 16B copy. LDS dest must be wave-uniform base + lane*16.
// ---------------------------------------------------------------------------
__device__ __forceinline__ void gload_lds16(const void* g, void* l) {
    __builtin_amdgcn_global_load_lds(
        (const __attribute__((address_space(1))) unsigned char*)g,
        (__attribute__((address_space(3))) unsigned char*)l,
        16, 0, 0);
}

// ---------------------------------------------------------------------------
// Fused preprocessing (unchanged): 4 weight transposes + x convert.
// ---------------------------------------------------------------------------
__global__ __launch_bounds__(256) void prep_kernel(const float* __restrict__ x,
                                                   const float* __restrict__ wq,
                                                   const float* __restrict__ wk,
                                                   const float* __restrict__ wv,
                                                   const float* __restrict__ wo,
                                                   __hip_bfloat16* __restrict__ wqkvT,
                                                   __hip_bfloat16* __restrict__ woT,
                                                   __hip_bfloat16* __restrict__ xb) {
    __shared__ float tile[32][33];
    const int bid = (int)blockIdx.x;
    const int tid = threadIdx.x;
    if (bid < 10240) {
        const float* src;
        __hip_bfloat16* dst;
        int C, gx, gy;
        if (bid < 4096)      { src = wq; dst = wqkvT; C = D_MODEL; gx = bid & 63; gy = bid >> 6; }
        else if (bid < 5120) { src = wk; dst = wqkvT + (size_t)D_MODEL * D_MODEL; C = KV_DIM; gx = (bid - 4096) & 15; gy = (bid - 4096) >> 4; }
        else if (bid < 6144) { src = wv; dst = wqkvT + (size_t)(D_MODEL + KV_DIM) * D_MODEL; C = KV_DIM; gx = (bid - 5120) & 15; gy = (bid - 5120) >> 4; }
        else                 { src = wo; dst = woT; C = D_MODEL; gx = (bid - 6144) & 63; gy = (bid - 6144) >> 6; }
        const int R = D_MODEL;
        const int bx = gx * 32, by = gy * 32;
        const int tx = tid & 31, ty = tid >> 5;
#pragma unroll
        for (int i = 0; i < 32; i += 8)
            tile[ty + i][tx] = src[(size_t)(by + ty + i) * C + bx + tx];
        __syncthreads();
#pragma unroll
        for (int i = 0; i < 32; i += 8)
            dst[(size_t)(bx + ty + i) * R + by + tx] = __float2bfloat16(tile[tx][ty + i]);
    } else {
        const int i = ((bid - 10240) * 256 + tid) * 8;
        const float4 a = *reinterpret_cast<const float4*>(x + i);
        const float4 b = *reinterpret_cast<const float4*>(x + i + 4);
        bf16x8 r;
        r[0] = (__bf16)a.x; r[1] = (__bf16)a.y; r[2] = (__bf16)a.z; r[3] = (__bf16)a.w;
        r[4] = (__bf16)b.x; r[5] = (__bf16)b.y; r[6] = (__bf16)b.z; r[7] = (__bf16)b.w;
        *reinterpret_cast<bf16x8*>(xb + i) = r;
    }
}

// ---------------------------------------------------------------------------
// Fused RoPE + V transpose (unchanged).
// ---------------------------------------------------------------------------
__global__ __launch_bounds__(256) void rope_v_kernel(__hip_bfloat16* __restrict__ QKV,
                                                     const float* __restrict__ cos_t,
                                                     const float* __restrict__ sin_t,
                                                     __hip_bfloat16* __restrict__ Vt) {
    __shared__ __align__(16) __bf16 vtile[64][72];
    const int bid = (int)blockIdx.x;
    const int tid = threadIdx.x;
    if (bid < 10240) {
        const int idx = bid * 256 + tid;
        const int i = idx & 31;
        const int hh = (idx >> 5) % (N_HEADS + N_KV);
        const int s = idx / (32 * (N_HEADS + N_KV));
        const float c = cos_t[s * 32 + i];
        const float sn = sin_t[s * 32 + i];
        int col; float scale;
        if (hh < N_HEADS) { col = hh * HEAD_DIM + 2 * i; scale = 0.125f * 1.44269504f; }
        else { col = D_MODEL + (hh - N_HEADS) * HEAD_DIM + 2 * i; scale = 1.0f; }
        __hip_bfloat16* p = &QKV[(size_t)s * QKV_N + col];
        const float re = __bfloat162float(p[0]);
        const float im = __bfloat162float(p[1]);
        p[0] = __float2bfloat16((re * c - im * sn) * scale);
        p[1] = __float2bfloat16((re * sn + im * c) * scale);
    } else {
        const int vb = bid - 10240;
        const int s0 = (vb & 31) * 64;
        const int hkv = vb >> 5;
        {
            const int r = tid >> 2;
            const int c0 = (tid & 3) * 16;
            const __hip_bfloat16* src = QKV + (size_t)(s0 + r) * QKV_N + D_MODEL + KV_DIM + hkv * HEAD_DIM + c0;
            *reinterpret_cast<bf16x8*>(&vtile[r][c0]) = *reinterpret_cast<const bf16x8*>(src);
            *reinterpret_cast<bf16x8*>(&vtile[r][c0 + 8]) = *reinterpret_cast<const bf16x8*>(src + 8);
        }
        __syncthreads();
        {
            const int d = tid >> 2;
            const int sc = (tid & 3) * 16;
            bf16x8 o0, o1;
#pragma unroll
            for (int j = 0; j < 8; ++j) { o0[j] = vtile[sc + j][d]; o1[j] = vtile[sc + 8 + j][d]; }
            __hip_bfloat16* dst = Vt + (size_t)(hkv * HEAD_DIM + d) * S_LEN + s0 + sc;
            *reinterpret_cast<bf16x8*>(dst) = o0;
            *reinterpret_cast<bf16x8*>(dst + 8) = o1;
        }
    }
}

// ---------------------------------------------------------------------------
// GEMM v9: same 128x128 tile / BK=64 / 2-phase prefetch / (row&7) swizzle
// as the proven R11 kernel, but 8 WAVES (512 thr, wave tile 64x32).
// Rationale: 64 KB LDS caps at 2 blocks/CU; with 256-thr blocks that was
// only 8 waves/CU (2/SIMD) -> vmcnt(0) drain exposed. Same tile at 512 thr
// doubles resident waves (16/CU): per-wave compute halves and twice as many
// independent waves interleave through each drain window.
// ---------------------------------------------------------------------------
__device__ inline void storeC(__hip_bfloat16* p, float v) { *p = __float2bfloat16(v); }
__device__ inline void storeC(float* p, float v) { *p = v; }

template <typename OutT>
__global__ __launch_bounds__(512) void gemm_bt(const __hip_bfloat16* __restrict__ A,
                                               const __hip_bfloat16* __restrict__ Bt,
                                               OutT* __restrict__ C,
                                               int M, int N, int K) {
    __shared__ __align__(16) __bf16 As[2][128 * 64];   // 16 KB x2
    __shared__ __align__(16) __bf16 Bs[2][128 * 64];   // 16 KB x2
    const int tid = threadIdx.x;
    const int w = tid >> 6, l = tid & 63;
    const int wr = w >> 2, wc = w & 3;          // 2x4 wave grid, wave tile 64x32
    const int l4 = l >> 4, l15 = l & 15;
    const int bm = blockIdx.y * 128, bn = blockIdx.x * 128;

    f32x4 acc[4][2];
#pragma unroll
    for (int i = 0; i < 4; ++i)
#pragma unroll
        for (int j = 0; j < 2; ++j) acc[i][j] = (f32x4){0.f, 0.f, 0.f, 0.f};

    // stage: 1024 16B-chunks per array; 512 threads -> 2 chunks each
    auto stage = [&](int buf, int k0) {
#pragma unroll
        for (int p = 0; p < 2; ++p) {
            const int chunk = p * 512 + tid;
            const int row = chunk >> 3;
            const int cs = (chunk & 7) ^ (row & 7);   // pre-swizzled source chunk
            gload_lds16(&A[(size_t)(bm + row) * K + k0 + cs * 8], &As[buf][chunk * 8]);
            gload_lds16(&Bt[(size_t)(bn + row) * K + k0 + cs * 8], &Bs[buf][chunk * 8]);
        }
    };

    const int nk = K >> 6;   // BK=64 steps
    stage(0, 0);
    asm volatile("s_waitcnt vmcnt(0)" ::: "memory");
    __builtin_amdgcn_s_barrier();

#pragma unroll 2
    for (int kt = 0; kt < nk; ++kt) {
        const int cur = kt & 1;
        if (kt + 1 < nk) stage(cur ^ 1, (kt + 1) * 64);   // prefetch next tile
#pragma unroll
        for (int ks = 0; ks < 2; ++ks) {
            bf16x8 a[4], b[2];
#pragma unroll
            for (int mi = 0; mi < 4; ++mi) {
                const int rr = wr * 64 + mi * 16 + l15;
                a[mi] = *reinterpret_cast<const bf16x8*>(
                    &As[cur][rr * 64 + (((ks * 4 + l4) ^ (rr & 7))) * 8]);
            }
#pragma unroll
            for (int ni = 0; ni < 2; ++ni) {
                const int rr = wc * 32 + ni * 16 + l15;
                b[ni] = *reinterpret_cast<const bf16x8*>(
                    &Bs[cur][rr * 64 + (((ks * 4 + l4) ^ (rr & 7))) * 8]);
            }
#pragma unroll
            for (int mi = 0; mi < 4; ++mi)
#pragma unroll
                for (int ni = 0; ni < 2; ++ni)
                    acc[mi][ni] = __builtin_amdgcn_mfma_f32_16x16x32_bf16(a[mi], b[ni], acc[mi][ni], 0, 0, 0);
        }
        asm volatile("s_waitcnt vmcnt(0)" ::: "memory");
        __builtin_amdgcn_s_barrier();
    }
#pragma unroll
    for (int mi = 0; mi < 4; ++mi)
#pragma unroll
        for (int ni = 0; ni < 2; ++ni)
#pragma unroll
            for (int r = 0; r < 4; ++r) {
                const int row = bm + wr * 64 + mi * 16 + l4 * 4 + r;
                const int col = bn + wc * 32 + ni * 16 + l15;
                storeC(&C[(size_t)row * N + col], acc[mi][ni][r]);
            }
}

// ---------------------------------------------------------------------------
// permlane32_swap helpers (unchanged).
// ---------------------------------------------------------------------------
#if __has_builtin(__builtin_amdgcn_permlane32_swap)
__device__ __forceinline__ void plswap(unsigned& x, unsigned& y, int) {
    uint2v r = __builtin_amdgcn_permlane32_swap(x, y, false, false);
    x = r[0]; y = r[1];
}
#else
__device__ __forceinline__ void plswap(unsigned& x, unsigned& y, int hi) {
    const unsigned px = __shfl_xor(x, 32, 64);
    const unsigned py = __shfl_xor(y, 32, 64);
    const unsigned nx = hi ? py : x;
    const unsigned ny = hi ? y : px;
    x = nx; y = ny;
}
#endif

__device__ __forceinline__ unsigned cvtpk_bf16(float lo, float hi) {
    unsigned w;
    asm("v_cvt_pk_bf16_f32 %0, %1, %2" : "=v"(w) : "v"(lo), "v"(hi));
    return w;
}
__device__ __forceinline__ float swap_max(float v, int hi) {
    unsigned x = __builtin_bit_cast(unsigned, v), y = x;
    plswap(x, y, hi);
    return fmaxf(__builtin_bit_cast(float, x), __builtin_bit_cast(float, y));
}
__device__ __forceinline__ float swap_add(float v, int hi) {
    unsigned x = __builtin_bit_cast(unsigned, v), y = x;
    plswap(x, y, hi);
    return __builtin_bit_cast(float, x) + __builtin_bit_cast(float, y);
}
template <int R0>
__device__ __forceinline__ bf16x8 build_pfrag(const f32x16& s, int hi) {
    unsigned A0 = cvtpk_bf16(s[R0 + 0], s[R0 + 1]);
    unsigned A1 = cvtpk_bf16(s[R0 + 2], s[R0 + 3]);
    unsigned B0 = cvtpk_bf16(s[R0 + 4], s[R0 + 5]);
    unsigned B1 = cvtpk_bf16(s[R0 + 6], s[R0 + 7]);
    plswap(A0, B0, hi);
    plswap(A1, B1, hi);
    uint4v u; u[0] = A0; u[1] = A1; u[2] = B0; u[3] = B1;
    return __builtin_bit_cast(bf16x8, u);
}

// ---------------------------------------------------------------------------
// Flash attention v12 = v11 + LPT dispatch order: blockIdx.x 0..27 are the
// 28 non-diagonal slices (full compute, heavy), 28..35 the 8 diagonal
// slices (half their tiles masked, light) -> light blocks fill the tail of
// the 1.1-generation schedule. Partial-group index g unchanged.
// ---------------------------------------------------------------------------
__global__ __launch_bounds__(512) void attn_kernel(const __hip_bfloat16* __restrict__ QKV,
                                                   const __hip_bfloat16* __restrict__ Vt,
                                                   __hip_bfloat16* __restrict__ O,
                                                   __hip_bfloat16* __restrict__ Opart,
                                                   float* __restrict__ ms,
                                                   int split) {
    const int h = blockIdx.y;
    const int hkv = h >> 2;
    int qc = 0, sl = 0, ns = 1;
    if (!split) {
        qc = 7 - (int)blockIdx.x;
    } else {
        const int x = (int)blockIdx.x;      // 0..35, LPT order
        if (x < 28) {
            // non-diagonal slices: q=1..7 each contributes q slices (sl<q)
            int cum = 0;
#pragma unroll
            for (int q = 1; q < 8; ++q) {
                if (x >= cum && x < cum + q) { qc = q; sl = x - cum; }
                cum += q;
            }
        } else {
            qc = x - 28; sl = qc;           // diagonal slices (incl. qc=0)
        }
        ns = qc + 1;
    }
    const int ntf = 4 * (qc + 1);
    const int t0 = split ? sl * 4 : 0;
    const int t1 = split ? min(t0 + 4, ntf) : ntf;

    const int tid = threadIdx.x;
    const int w = tid >> 6, l = tid & 63;
    const int lq = l & 31, hi = l >> 5;
    const int q0w = qc * 256 + w * 32;
    const int qlane = q0w + lq;

    __shared__ __align__(16) __bf16 Ks[2][64 * 64];  // [kv][d] swizzled
    __shared__ __align__(16) __bf16 Vs[2][64 * 64];  // [d][kv] swizzled

    const __hip_bfloat16* Kg = QKV + D_MODEL + hkv * HEAD_DIM;       // [s][QKV_N]
    const __hip_bfloat16* Vg = Vt + (size_t)hkv * HEAD_DIM * S_LEN;  // [d][S]

    auto stage = [&](int buf, int kv0) {
        const int chunk = tid;                    // 0..511
        const int r = chunk >> 3;                 // row 0..63
        const int cs = (chunk & 7) ^ (r & 7);     // pre-swizzled source chunk
        gload_lds16(&Kg[(size_t)(kv0 + r) * QKV_N + cs * 8], &Ks[buf][chunk * 8]);
        gload_lds16(&Vg[(size_t)r * S_LEN + kv0 + cs * 8], &Vs[buf][chunk * 8]);
    };

    // Q as B-operand: lane holds Q[qlane][16f + 8*hi + e]
    bf16x8 qf[4];
#pragma unroll
    for (int f = 0; f < 4; ++f)
        qf[f] = *reinterpret_cast<const bf16x8*>(
            &QKV[(size_t)qlane * QKV_N + h * HEAD_DIM + 16 * f + 8 * hi]);

    f32x16 o0, o1;
#pragma unroll
    for (int r = 0; r < 16; ++r) { o0[r] = 0.f; o1[r] = 0.f; }
    float m_run = -__builtin_inff(), s_run = 0.f;

    stage(0, t0 * 64);

#pragma unroll 1
    for (int t = t0; t < t1; ++t) {
        __syncthreads();                       // tile t staged (vmcnt drained)
        if (t + 1 < t1) stage((t + 1 - t0) & 1, (t + 1) * 64);
        const int kv0 = t * 64;
        if (kv0 <= q0w + 31) {                 // wave-uniform: skip fully-masked
            const __bf16* Kb = Ks[(t - t0) & 1];
            const __bf16* Vb = Vs[(t - t0) & 1];

            // S^T = K · Q^T  (two 32-kv sub-tiles)
            f32x16 s0, s1;
#pragma unroll
            for (int r = 0; r < 16; ++r) { s0[r] = 0.f; s1[r] = 0.f; }
            __builtin_amdgcn_s_setprio(1);
#pragma unroll
            for (int f = 0; f < 4; ++f) {
                const int rr0 = lq;
                const int rr1 = 32 + lq;
                const bf16x8 ka0 = *reinterpret_cast<const bf16x8*>(
                    &Kb[rr0 * 64 + (((2 * f + hi) ^ (rr0 & 7))) * 8]);
                const bf16x8 ka1 = *reinterpret_cast<const bf16x8*>(
                    &Kb[rr1 * 64 + (((2 * f + hi) ^ (rr1 & 7))) * 8]);
                s0 = __builtin_amdgcn_mfma_f32_32x32x16_bf16(ka0, qf[f], s0, 0, 0, 0);
                s1 = __builtin_amdgcn_mfma_f32_32x32x16_bf16(ka1, qf[f], s1, 0, 0, 0);
            }
            __builtin_amdgcn_s_setprio(0);
            // causal mask (only tiles crossing the diagonal)
            if (kv0 + 63 > q0w) {
#pragma unroll
                for (int r = 0; r < 16; ++r) {
                    const int kvb = (r & 3) + 8 * (r >> 2) + 4 * hi;
                    if (kv0 + kvb > qlane) s0[r] = -__builtin_inff();
                    if (kv0 + 32 + kvb > qlane) s1[r] = -__builtin_inff();
                }
            }
            // row max: tree over own 32 regs, then partner exchange
            float ta = fmaxf(s0[0], s1[0]), tb = fmaxf(s0[1], s1[1]);
            float tc = fmaxf(s0[2], s1[2]), td = fmaxf(s0[3], s1[3]);
#pragma unroll
            for (int r = 4; r < 16; r += 4) {
                ta = fmaxf(ta, fmaxf(s0[r], s1[r]));
                tb = fmaxf(tb, fmaxf(s0[r + 1], s1[r + 1]));
                tc = fmaxf(tc, fmaxf(s0[r + 2], s1[r + 2]));
                td = fmaxf(td, fmaxf(s0[r + 3], s1[r + 3]));
            }
            const float m_row = swap_max(fmaxf(fmaxf(ta, tb), fmaxf(tc, td)), hi);

            // defer-max: skip rescale when max grew by <= 8 (exp2 domain)
            if (!__all(m_row <= m_run + 8.0f)) {
                const float mnew = fmaxf(m_run, m_row);
                const float corr = exp2f(m_run - mnew);
                m_run = mnew;
                s_run *= corr;
#pragma unroll
                for (int r = 0; r < 16; ++r) { o0[r] *= corr; o1[r] *= corr; }
            }
            // P = exp2(S - m_run)
#pragma unroll
            for (int r = 0; r < 16; ++r) {
                s0[r] = exp2f(s0[r] - m_run);
                s1[r] = exp2f(s1[r] - m_run);
            }
            // row sum
            float ua = s0[0] + s1[0], ub = s0[1] + s1[1];
            float uc = s0[2] + s1[2], ud = s0[3] + s1[3];
#pragma unroll
            for (int r = 4; r < 16; r += 4) {
                ua += s0[r] + s1[r];
                ub += s0[r + 1] + s1[r + 1];
                uc += s0[r + 2] + s1[r + 2];
                ud += s0[r + 3] + s1[r + 3];
            }
            s_run += swap_add((ua + ub) + (uc + ud), hi);

            // P fragments (k-steps of 16 kv)
            bf16x8 pa[4];
            pa[0] = build_pfrag<0>(s0, hi);
            pa[1] = build_pfrag<8>(s0, hi);
            pa[2] = build_pfrag<0>(s1, hi);
            pa[3] = build_pfrag<8>(s1, hi);

            // O^T += V^T · P^T
            __builtin_amdgcn_s_setprio(1);
#pragma unroll
            for (int ks = 0; ks < 4; ++ks) {
                const int rv0 = lq;
                const int rv1 = 32 + lq;
                const bf16x8 va0 = *reinterpret_cast<const bf16x8*>(
                    &Vb[rv0 * 64 + (((2 * ks + hi) ^ (rv0 & 7))) * 8]);
                const bf16x8 va1 = *reinterpret_cast<const bf16x8*>(
                    &Vb[rv1 * 64 + (((2 * ks + hi) ^ (rv1 & 7))) * 8]);
                o0 = __builtin_amdgcn_mfma_f32_32x32x16_bf16(va0, pa[ks], o0, 0, 0, 0);
                o1 = __builtin_amdgcn_mfma_f32_32x32x16_bf16(va1, pa[ks], o1, 0, 0, 0);
            }
            __builtin_amdgcn_s_setprio(0);
        }
    }

    if (ns == 1) {
        // direct normalized write: O^T[dv][q] -> O[q][h*64+dv]
        const float inv = 1.0f / s_run;
        __hip_bfloat16* orow = O + (size_t)qlane * D_MODEL + h * HEAD_DIM;
#pragma unroll
        for (int rr = 0; rr < 4; ++rr) {
            {
                uint2v u;
                u[0] = cvtpk_bf16(o0[4 * rr] * inv, o0[4 * rr + 1] * inv);
                u[1] = cvtpk_bf16(o0[4 * rr + 2] * inv, o0[4 * rr + 3] * inv);
                *reinterpret_cast<uint2v*>(orow + 8 * rr + 4 * hi) = u;
            }
            {
                uint2v u;
                u[0] = cvtpk_bf16(o1[4 * rr] * inv, o1[4 * rr + 1] * inv);
                u[1] = cvtpk_bf16(o1[4 * rr + 2] * inv, o1[4 * rr + 3] * inv);
                *reinterpret_cast<uint2v*>(orow + 32 + 8 * rr + 4 * hi) = u;
            }
        }
    } else {
        // partial write: unnormalized bf16 O + (m, s) per row
        static const int kCum2d[8] = {0, 1, 3, 6, 10, 15, 21, 28};
        const int g = h * 36 + kCum2d[qc] + sl;
        const int row = w * 32 + lq;                      // 0..255 within chunk
        __hip_bfloat16* pb = Opart + ((size_t)g * 256 + row) * 64;
#pragma unroll
        for (int rr = 0; rr < 4; ++rr) {
            {
                uint2v u;
                u[0] = cvtpk_bf16(o0[4 * rr], o0[4 * rr + 1]);
                u[1] = cvtpk_bf16(o0[4 * rr + 2], o0[4 * rr + 3]);
                *reinterpret_cast<uint2v*>(pb + 8 * rr + 4 * hi) = u;
            }
            {
                uint2v u;
                u[0] = cvtpk_bf16(o1[4 * rr], o1[4 * rr + 1]);
                u[1] = cvtpk_bf16(o1[4 * rr + 2], o1[4 * rr + 3]);
                *reinterpret_cast<uint2v*>(pb + 32 + 8 * rr + 4 * hi) = u;
            }
        }
        if (hi == 0) {
            const size_t mi = (size_t)g * 256 + row;
            ms[mi * 2] = m_run;
            ms[mi * 2 + 1] = s_run;
        }
    }
}

// ---------------------------------------------------------------------------
// Merge split-KV partials for qc >= 1 (unchanged).
// ---------------------------------------------------------------------------
__device__ __constant__ int kCum2[8] = {0, 1, 3, 6, 10, 15, 21, 28};

__global__ __launch_bounds__(256) void attn_merge(const __hip_bfloat16* __restrict__ Opart,
                                                  const float* __restrict__ ms,
                                                  __hip_bfloat16* __restrict__ O) {
    const int qc = 1 + blockIdx.x;                    // 1..7
    const int h = blockIdx.z;
    const int tid = threadIdx.x;
    const int row = blockIdx.y * 32 + (tid >> 3);     // 0..255
    const int dv0 = (tid & 7) * 8;
    const int ns = qc + 1;                            // 2..8
    const int g0 = h * 36 + kCum2[qc];

    float mv[8], sv[8];
    float M = -__builtin_inff();
#pragma unroll
    for (int s = 0; s < 8; ++s) {
        if (s < ns) {
            const size_t mi = (size_t)(g0 + s) * 256 + row;
            mv[s] = ms[mi * 2];
            sv[s] = ms[mi * 2 + 1];
            M = fmaxf(M, mv[s]);
        }
    }
    float S = 0.f;
    float acc[8];
#pragma unroll
    for (int j = 0; j < 8; ++j) acc[j] = 0.f;
#pragma unroll
    for (int s = 0; s < 8; ++s) {
        if (s < ns) {
            const float wgt = exp2f(mv[s] - M);
            S += wgt * sv[s];
            const bf16x8 v = *reinterpret_cast<const bf16x8*>(
                &Opart[((size_t)(g0 + s) * 256 + row) * 64 + dv0]);
#pragma unroll
            for (int j = 0; j < 8; ++j) acc[j] += wgt * (float)v[j];
        }
    }
    const float inv = 1.0f / S;
    uint4v u;
    u[0] = cvtpk_bf16(acc[0] * inv, acc[1] * inv);
    u[1] = cvtpk_bf16(acc[2] * inv, acc[3] * inv);
    u[2] = cvtpk_bf16(acc[4] * inv, acc[5] * inv);
    u[3] = cvtpk_bf16(acc[6] * inv, acc[7] * inv);
    *reinterpret_cast<uint4v*>(&O[(size_t)(qc * 256 + row) * D_MODEL + h * HEAD_DIM + dv0]) = u;
}

// ---------------------------------------------------------------------------
// Launch: 6 dispatches.
// ---------------------------------------------------------------------------
extern "C" void kernel_launch(void* const* d_in, const int* in_sizes, int n_in,
                              void* d_out, int out_size, void* d_ws, size_t ws_size,
                              hipStream_t stream) {
    const float* x  = (const float*)d_in[0];
    const float* wq = (const float*)d_in[1];
    const float* wk = (const float*)d_in[2];
    const float* wv = (const float*)d_in[3];
    const float* wo = (const float*)d_in[4];
    const float* fc = (const float*)d_in[5];
    const float* fs = (const float*)d_in[6];
    float* out = (float*)d_out;

    char* ws = (char*)d_ws;
    __hip_bfloat16* wqkvT = (__hip_bfloat16*)(ws);                 // [3072][2048] bf16, 12 MiB
    __hip_bfloat16* woT   = (__hip_bfloat16*)(ws + (12u << 20));   // [2048][2048], 8 MiB
    __hip_bfloat16* attnb = (__hip_bfloat16*)(ws + (20u << 20));   // [2048][2048], 8 MiB
    __hip_bfloat16* xb    = (__hip_bfloat16*)(ws + (28u << 20));   // [2048][2048], 8 MiB
    __hip_bfloat16* QKV   = (__hip_bfloat16*)(ws + (36u << 20));   // [2048][3072], 12 MiB
    __hip_bfloat16* Vt    = (__hip_bfloat16*)(ws + (48u << 20));   // [512][2048], 2 MiB
    float*          msb   = (float*)(ws + (50u << 20));            // 1152*256*2 f32, 2.4 MiB
    __hip_bfloat16* Opart = (__hip_bfloat16*)(ws + (53u << 20));   // 1152*256*64 bf16, 38 MiB

    const int split = (ws_size >= (96ull << 20)) ? 1 : 0;

    // fused preprocessing: all weight transposes + x convert (1 launch)
    prep_kernel<<<12288, 256, 0, stream>>>(x, wq, wk, wv, wo, wqkvT, woT, xb);

    // fused QKV projection: [2048][3072]  (8-wave blocks)
    gemm_bt<__hip_bfloat16><<<dim3(QKV_N / 128, S_LEN / 128), 512, 0, stream>>>(xb, wqkvT, QKV, S_LEN, QKV_N, D_MODEL);

    // fused RoPE (Q,K) + V transpose (1 launch)
    rope_v_kernel<<<10496, 256, 0, stream>>>(QKV, fc, fs, Vt);

    // causal GQA flash attention (8 waves, 256 q-rows/block, deep split-KV, LPT)
    if (split) {
        attn_kernel<<<dim3(36, N_HEADS), 512, 0, stream>>>(QKV, Vt, attnb, Opart, msb, 1);
        attn_merge<<<dim3(7, 8, N_HEADS), 256, 0, stream>>>(Opart, msb, attnb);
    } else {
        attn_kernel<<<dim3(8, N_HEADS), 512, 0, stream>>>(QKV, Vt, attnb, Opart, msb, 0);
    }

    // output projection -> f32 (8-wave blocks)
    gemm_bt<float><<<dim3(D_MODEL / 128, S_LEN / 128), 512, 0, stream>>>(attnb, woT, out, S_LEN, D_MODEL, D_MODEL);

    (void)in_sizes; (void)n_in; (void)out_size;
}